// Round 1
// baseline (999.865 us; speedup 1.0000x reference)
//
#include <hip/hip_runtime.h>
#include <math.h>

#define N_ROWS 262144
#define K_COMP 256
#define D_DIM  128
#define BN 64
#define BD 16
#define XSTRIDE 68   // padded row length for transposed x tiles (bank-conflict ~2-way = free)

static __device__ __constant__ float kLOG2PI = 1.8378770664093453f;

// ---------------- prep: B matrices, sigma, per-k constants, zero Q ----------------
__global__ __launch_bounds__(128) void gmm_prep(
    const float* __restrict__ means, const float* __restrict__ log_stds,
    const float* __restrict__ weights,
    float* __restrict__ ivT, float* __restrict__ m2T,
    float* __restrict__ sigma, float* __restrict__ ck, double* __restrict__ wsq)
{
    int k = blockIdx.x;     // 0..255
    int d = threadIdx.x;    // 0..127
    float ls = log_stds[k * D_DIM + d];
    float mu = means[k * D_DIM + d];
    float iv = expf(-2.0f * ls);
    ivT[d * K_COMP + k] = iv;
    m2T[d * K_COMP + k] = -2.0f * mu * iv;
    sigma[k * D_DIM + d] = expf(ls);

    float c = mu * mu * iv;
    float s = ls;
    // weights logsumexp over K=256 (each thread holds 2)
    float w1 = weights[d], w2 = weights[d + 128];
    float wm = fmaxf(w1, w2);

    __shared__ float red[8];
    int lane = d & 63, wv = d >> 6;
    #pragma unroll
    for (int o = 32; o > 0; o >>= 1) {
        c += __shfl_down(c, o, 64);
        s += __shfl_down(s, o, 64);
        wm = fmaxf(wm, __shfl_down(wm, o, 64));
    }
    if (lane == 0) { red[wv] = c; red[2 + wv] = s; red[4 + wv] = wm; }
    __syncthreads();
    float csum = red[0] + red[1];
    float ssum = red[2] + red[3];
    float wmax = fmaxf(red[4], red[5]);
    float we = expf(w1 - wmax) + expf(w2 - wmax);
    #pragma unroll
    for (int o = 32; o > 0; o >>= 1) we += __shfl_down(we, o, 64);
    if (lane == 0) red[6 + wv] = we;
    __syncthreads();
    if (d == 0) {
        float wsum = red[6] + red[7];
        float lw = weights[k] - (wmax + logf(wsum));   // log_softmax(weights)[k]
        ck[k] = -0.5f * (csum + (float)D_DIM * kLOG2PI) - ssum + lw;
        if (k == 0) *wsq = 0.0;
    }
}

// ---------------- main: quad GEMM + softmax/argmax + resample ----------------
__global__ __launch_bounds__(256, 3) void gmm_main(
    const float* __restrict__ x, const float* __restrict__ noise,
    const float* __restrict__ means, const float* __restrict__ sigma,
    const float* __restrict__ ivT, const float* __restrict__ m2T,
    const float* __restrict__ ck,
    float* __restrict__ out_x, float* __restrict__ out_idx, double* __restrict__ wsq)
{
    __shared__ float sIv[BD * K_COMP];
    __shared__ float sM2[BD * K_COMP];
    __shared__ float sX [BD * XSTRIDE];
    __shared__ float sX2[BD * XSTRIDE];
    __shared__ float sCk[K_COMP];
    __shared__ float sQ;

    const int tid = threadIdx.x;
    const int tx = tid & 15;      // col group: cols q*64 + tx*4 + j
    const int ty = tid >> 4;      // row group: rows ty*4 + rr
    const long n0 = (long)blockIdx.x * BN;

    sCk[tid] = ck[tid];
    if (tid == 0) sQ = 0.0f;

    float acc[4][16];
    #pragma unroll
    for (int r = 0; r < 4; ++r)
        #pragma unroll
        for (int i = 0; i < 16; ++i) acc[r][i] = 0.0f;

    const int r = tid >> 2;            // 0..63  (staging row)
    const int dsub = (tid & 3) * 4;    // 0,4,8,12

    for (int d0 = 0; d0 < D_DIM; d0 += BD) {
        // ---- stage B tiles (coalesced, 2-way LDS bank alias = free) ----
        #pragma unroll
        for (int i = 0; i < BD; ++i) {
            sIv[i * K_COMP + tid] = ivT[(d0 + i) * K_COMP + tid];
            sM2[i * K_COMP + tid] = m2T[(d0 + i) * K_COMP + tid];
        }
        // ---- stage x tile, transposed, plus squares ----
        float4 xv = *(const float4*)&x[(n0 + r) * D_DIM + d0 + dsub];
        {
            float xe[4] = {xv.x, xv.y, xv.z, xv.w};
            #pragma unroll
            for (int j = 0; j < 4; ++j) {
                sX [(dsub + j) * XSTRIDE + r] = xe[j];
                sX2[(dsub + j) * XSTRIDE + r] = xe[j] * xe[j];
            }
        }
        __syncthreads();

        #pragma unroll 4
        for (int dd = 0; dd < BD; ++dd) {
            float4 xr4  = *(const float4*)&sX [dd * XSTRIDE + ty * 4];
            float4 x2r4 = *(const float4*)&sX2[dd * XSTRIDE + ty * 4];
            float xe[4]  = {xr4.x, xr4.y, xr4.z, xr4.w};
            float x2e[4] = {x2r4.x, x2r4.y, x2r4.z, x2r4.w};
            #pragma unroll
            for (int q = 0; q < 4; ++q) {
                float4 iv4 = *(const float4*)&sIv[dd * K_COMP + q * 64 + tx * 4];
                float4 m24 = *(const float4*)&sM2[dd * K_COMP + q * 64 + tx * 4];
                float ive[4] = {iv4.x, iv4.y, iv4.z, iv4.w};
                float m2e[4] = {m24.x, m24.y, m24.z, m24.w};
                #pragma unroll
                for (int rr = 0; rr < 4; ++rr)
                    #pragma unroll
                    for (int j = 0; j < 4; ++j)
                        acc[rr][q * 4 + j] += x2e[rr] * ive[j] + xe[rr] * m2e[j];
            }
        }
        __syncthreads();
    }

    // ---- epilogue: per-row softmax / argmax / Q / resample ----
    float ckv[16];
    #pragma unroll
    for (int q = 0; q < 4; ++q)
        #pragma unroll
        for (int j = 0; j < 4; ++j) ckv[q * 4 + j] = sCk[q * 64 + tx * 4 + j];

    float qacc = 0.0f;
    #pragma unroll 1
    for (int rr = 0; rr < 4; ++rr) {
        const long n = n0 + ty * 4 + rr;
        float jv[16];
        float m = -INFINITY; int am = 0;
        #pragma unroll
        for (int i = 0; i < 16; ++i) {
            float v = -0.5f * acc[rr][i] + ckv[i];
            jv[i] = v;
            int c = (i >> 2) * 64 + tx * 4 + (i & 3);
            if (v > m || (v == m && c < am)) { m = v; am = c; }
        }
        // 16-lane group reductions (a row group is contiguous lanes within one wave)
        #pragma unroll
        for (int o = 1; o < 16; o <<= 1) {
            float om = __shfl_xor(m, o, 16);
            int   oa = __shfl_xor(am, o, 16);
            if (om > m || (om == m && oa < am)) { m = om; am = oa; }
        }
        float es = 0.0f, qs = 0.0f;
        #pragma unroll
        for (int i = 0; i < 16; ++i) {
            float e = expf(jv[i] - m);
            es += e; qs += e * jv[i];
        }
        #pragma unroll
        for (int o = 1; o < 16; o <<= 1) {
            es += __shfl_xor(es, o, 16);
            qs += __shfl_xor(qs, o, 16);
        }
        qacc += qs / es;   // sum_k p_k * joint_k for this row

        // resample: out = means[idx] + sigma[idx]*noise*0.1 ; 16 lanes cover 128 d
        const int idx = am;
        const float4* mrow = (const float4*)&means[idx * D_DIM];
        const float4* srow = (const float4*)&sigma[idx * D_DIM];
        const float4* nrow = (const float4*)&noise[n * D_DIM];
        float4*       orow = (float4*)&out_x[n * D_DIM];
        #pragma unroll
        for (int q = 0; q < 2; ++q) {
            int di = q * 16 + tx;          // float4 index -> d = q*64 + tx*4
            float4 mv = mrow[di], sv = srow[di], nv = nrow[di];
            float4 ov;
            ov.x = mv.x + sv.x * nv.x * 0.1f;
            ov.y = mv.y + sv.y * nv.y * 0.1f;
            ov.z = mv.z + sv.z * nv.z * 0.1f;
            ov.w = mv.w + sv.w * nv.w * 0.1f;
            orow[di] = ov;
        }
        if (tx == 0) out_idx[n] = (float)idx;
    }

    // block Q: each 16-lane group holds identical qacc; butterfly across groups
    qacc += __shfl_xor(qacc, 16, 64);
    qacc += __shfl_xor(qacc, 32, 64);
    if ((tid & 63) == 0) atomicAdd(&sQ, qacc);
    __syncthreads();
    if (tid == 0) atomicAdd(wsq, (double)sQ);
}

__global__ void gmm_finalize(const double* __restrict__ wsq, float* __restrict__ out_q)
{
    *out_q = (float)(*wsq * (1.0 / ((double)N_ROWS * (double)K_COMP)));
}

extern "C" void kernel_launch(void* const* d_in, const int* in_sizes, int n_in,
                              void* d_out, int out_size, void* d_ws, size_t ws_size,
                              hipStream_t stream)
{
    const float* x        = (const float*)d_in[0];
    const float* means    = (const float*)d_in[1];
    const float* log_stds = (const float*)d_in[2];
    const float* weights  = (const float*)d_in[3];
    const float* noise    = (const float*)d_in[4];

    float* out_x   = (float*)d_out;                          // [N, D]
    float* out_idx = (float*)d_out + (size_t)N_ROWS * D_DIM; // [N]
    float* out_q   = out_idx + N_ROWS;                       // scalar

    // ws layout (floats): ivT[128*256] | m2T[128*256] | sigma[256*128] | ck[256] | (double) wsq
    float* ws    = (float*)d_ws;
    float* ivT   = ws;
    float* m2T   = ws + 32768;
    float* sigma = ws + 65536;
    float* ck    = ws + 98304;
    double* wsq  = (double*)(ws + 98560);

    hipLaunchKernelGGL(gmm_prep, dim3(K_COMP), dim3(D_DIM), 0, stream,
                       means, log_stds, weights, ivT, m2T, sigma, ck, wsq);
    hipLaunchKernelGGL(gmm_main, dim3(N_ROWS / BN), dim3(256), 0, stream,
                       x, noise, means, sigma, ivT, m2T, ck, out_x, out_idx, wsq);
    hipLaunchKernelGGL(gmm_finalize, dim3(1), dim3(1), 0, stream, wsq, out_q);
}